// Round 3
// baseline (566.450 us; speedup 1.0000x reference)
//
#include <hip/hip_runtime.h>
#include <hip/hip_bf16.h>
#include <stdint.h>

#define H       2048
#define LOGH    11
#define T_TOK   4096
#define NEXP    8
#define NATOM   64
#define NS      16384

typedef short bf16x8 __attribute__((ext_vector_type(8)));
typedef float f32x4  __attribute__((ext_vector_type(4)));

// ---------------- convert x and W to bf16 (RNE) ----------------
__global__ __launch_bounds__(256) void cvt_kernel(
    const float* __restrict__ x, const float* __restrict__ W,
    unsigned short* __restrict__ xb, unsigned short* __restrict__ wb) {
  const int TH = T_TOK * H;
  const int WH = H * H;
  const int total4 = (TH + WH) / 4;
  for (int i = blockIdx.x * blockDim.x + threadIdx.x; i < total4;
       i += gridDim.x * blockDim.x) {
    int e0 = i * 4;
    const float* src;
    unsigned short* dst;
    if (e0 < TH) { src = x + e0; dst = xb + e0; }
    else         { src = W + (e0 - TH); dst = wb + (e0 - TH); }
    float4 v = *reinterpret_cast<const float4*>(src);
    ushort4 o;
    {
      union { float f; unsigned u; } c;
      c.f = v.x; c.u += 0x7fff + ((c.u >> 16) & 1); o.x = (unsigned short)(c.u >> 16);
      c.f = v.y; c.u += 0x7fff + ((c.u >> 16) & 1); o.y = (unsigned short)(c.u >> 16);
      c.f = v.z; c.u += 0x7fff + ((c.u >> 16) & 1); o.z = (unsigned short)(c.u >> 16);
      c.f = v.w; c.u += 0x7fff + ((c.u >> 16) & 1); o.w = (unsigned short)(c.u >> 16);
    }
    *reinterpret_cast<ushort4*>(dst) = o;
  }
}

// ---------------- weighted[e][s] = (softmax(eaw[e]) @ atoms)[s] * sigmoid(imp[e][s]) ----------------
__global__ __launch_bounds__(256) void weighted_kernel(
    const float* __restrict__ eaw, const float* __restrict__ atoms,
    const float* __restrict__ importance, float* __restrict__ weighted) {
  __shared__ float p[NATOM];
  const int e = blockIdx.x >> 3;
  const int chunk = blockIdx.x & 7;
  const int tid = threadIdx.x;
  if (tid < NATOM) p[tid] = eaw[e * NATOM + tid];
  __syncthreads();
  if (tid == 0) {
    float m = p[0];
    for (int a = 1; a < NATOM; ++a) m = fmaxf(m, p[a]);
    float s = 0.f;
    for (int a = 0; a < NATOM; ++a) { p[a] = expf(p[a] - m); s += p[a]; }
    float inv = 1.f / s;
    for (int a = 0; a < NATOM; ++a) p[a] *= inv;
  }
  __syncthreads();
  const int base = chunk * 2048 + tid;
  for (int it = 0; it < 8; ++it) {
    int s = base + it * 256;
    float acc = 0.f;
#pragma unroll 16
    for (int a = 0; a < NATOM; ++a) acc = fmaf(p[a], atoms[a * NS + s], acc);
    float imp = importance[e * NS + s];
    float sig = 1.f / (1.f + expf(-imp));
    weighted[e * NS + s] = acc * sig;
  }
}

// ---------------- bf16 MFMA GEMM: out[m][n] = sum_k xb[m][k] * wb[n][k] ----------------
__global__ __launch_bounds__(256) void gemm_kernel(
    const unsigned short* __restrict__ xb, const unsigned short* __restrict__ wb,
    float* __restrict__ out) {
  __shared__ __align__(16) unsigned short aLds[128 * 32];
  __shared__ __align__(16) unsigned short bLds[128 * 32];
  const int tid  = threadIdx.x;
  const int wave = tid >> 6;
  const int lane = tid & 63;
  const int m0 = blockIdx.y * 128;
  const int n0 = blockIdx.x * 128;
  const int wr = wave >> 1;
  const int wc = wave & 1;

  f32x4 acc[4][4];
#pragma unroll
  for (int i = 0; i < 4; ++i)
#pragma unroll
    for (int j = 0; j < 4; ++j)
#pragma unroll
      for (int r = 0; r < 4; ++r) acc[i][j][r] = 0.f;

  const int srow = lane >> 2;
  const int kcol = (lane & 3) * 8;

  for (int k0 = 0; k0 < H; k0 += 32) {
#pragma unroll
    for (int p = 0; p < 2; ++p) {
      const int g = p * 4 + wave;
      const unsigned short* ga = xb + (size_t)(m0 + g * 16 + srow) * H + k0 + kcol;
      const unsigned short* gb = wb + (size_t)(n0 + g * 16 + srow) * H + k0 + kcol;
      __builtin_amdgcn_global_load_lds(
          (const __attribute__((address_space(1))) unsigned int*)ga,
          (__attribute__((address_space(3))) unsigned int*)(aLds + g * 16 * 32), 16, 0, 0);
      __builtin_amdgcn_global_load_lds(
          (const __attribute__((address_space(1))) unsigned int*)gb,
          (__attribute__((address_space(3))) unsigned int*)(bLds + g * 16 * 32), 16, 0, 0);
    }
    __syncthreads();

    const int kc = (lane >> 4) * 8;
    const int ar = wr * 64 + (lane & 15);
    const int br = wc * 64 + (lane & 15);
    bf16x8 af[4], bfr[4];
#pragma unroll
    for (int i = 0; i < 4; ++i)
      af[i] = *reinterpret_cast<const bf16x8*>(aLds + (ar + i * 16) * 32 + kc);
#pragma unroll
    for (int j = 0; j < 4; ++j)
      bfr[j] = *reinterpret_cast<const bf16x8*>(bLds + (br + j * 16) * 32 + kc);
#pragma unroll
    for (int i = 0; i < 4; ++i)
#pragma unroll
      for (int j = 0; j < 4; ++j)
        acc[i][j] = __builtin_amdgcn_mfma_f32_16x16x32_bf16(af[i], bfr[j], acc[i][j], 0, 0, 0);
    __syncthreads();
  }

  const int cr = (lane >> 4) * 4;
  const int cc = lane & 15;
#pragma unroll
  for (int i = 0; i < 4; ++i)
#pragma unroll
    for (int j = 0; j < 4; ++j)
#pragma unroll
      for (int r = 0; r < 4; ++r)
        out[(size_t)(m0 + wr * 64 + i * 16 + cr + r) * H + (n0 + wc * 64 + j * 16 + cc)] =
            acc[i][j][r];
}

// ---------------- gate: one wave per token, exact fp32 top-2 ----------------
__global__ __launch_bounds__(256) void gate_kernel(
    const float* __restrict__ x, const float* __restrict__ gate_w,
    float4* __restrict__ tokInfo) {
  const int wv = threadIdx.x >> 6;
  const int lane = threadIdx.x & 63;
  const int t = blockIdx.x * 4 + wv;
  const float4* xr = reinterpret_cast<const float4*>(x + (size_t)t * H);

  float accs[NEXP];
#pragma unroll
  for (int e = 0; e < NEXP; ++e) accs[e] = 0.f;
#pragma unroll
  for (int it = 0; it < 8; ++it) {
    const int j4 = it * 64 + lane;  // float4 index within row (0..511)
    float4 xv = xr[j4];
#pragma unroll
    for (int e = 0; e < NEXP; ++e) {
      float4 gv = reinterpret_cast<const float4*>(gate_w + (size_t)e * H)[j4];
      accs[e] = fmaf(xv.x, gv.x, accs[e]);
      accs[e] = fmaf(xv.y, gv.y, accs[e]);
      accs[e] = fmaf(xv.z, gv.z, accs[e]);
      accs[e] = fmaf(xv.w, gv.w, accs[e]);
    }
  }
#pragma unroll
  for (int e = 0; e < NEXP; ++e) {
    float v = accs[e];
#pragma unroll
    for (int off = 32; off > 0; off >>= 1) v += __shfl_down(v, off);
    accs[e] = v;
  }
  if (lane == 0) {
    float lg[NEXP];
#pragma unroll
    for (int e = 0; e < NEXP; ++e) lg[e] = fminf(fmaxf(accs[e], -50.f), 50.f);
    int e0 = 0; float w0 = lg[0];
#pragma unroll
    for (int e = 1; e < NEXP; ++e) { if (lg[e] > w0) { w0 = lg[e]; e0 = e; } }
    int e1 = -1; float w1 = -3.4e38f;
#pragma unroll
    for (int e = 0; e < NEXP; ++e) {
      if (e == e0) continue;
      if (lg[e] > w1) { w1 = lg[e]; e1 = e; }
    }
    const float r1 = expf(w1 - w0);  // <= 1
    float4 ti;
    ti.x = 1.f / (1.f + r1);
    ti.y = r1 / (1.f + r1);
    ti.z = __int_as_float(e0);
    ti.w = __int_as_float(e1);
    tokInfo[t] = ti;
  }
}

// ---------------- scatter: 4 tokens/block, wave = token ----------------
__global__ __launch_bounds__(256) void scatter_kernel(
    const float* __restrict__ x, const float* __restrict__ weighted,
    const int* __restrict__ mask_idx, const float4* __restrict__ tokInfo,
    float* __restrict__ out) {
  __shared__ float xrow[4][H];   // 32 KB
  __shared__ float acc[4][H];    // 32 KB
  const int tid  = threadIdx.x;
  const int wv   = tid >> 6;
  const int lane = tid & 63;
  const int t0   = blockIdx.x * 4;

  // cooperative: copy 4 contiguous x rows into LDS, zero acc
  {
    const float4* xsrc = reinterpret_cast<const float4*>(x + (size_t)t0 * H);
    float4* xdst = reinterpret_cast<float4*>(&xrow[0][0]);
    float4* adst = reinterpret_cast<float4*>(&acc[0][0]);
    float4 z; z.x = z.y = z.z = z.w = 0.f;
#pragma unroll
    for (int i = 0; i < 8; ++i) {
      xdst[tid + i * 256] = xsrc[tid + i * 256];
      adst[tid + i * 256] = z;
    }
  }
  __syncthreads();

  const int t = t0 + wv;
  const float4 ti = tokInfo[t];
  const float rw0 = ti.x, rw1 = ti.y;
  const int e0 = __float_as_int(ti.z);
  const int e1 = __float_as_int(ti.w);

  const int4*   mask4 = reinterpret_cast<const int4*>(mask_idx);
  const float4* w0p4  = reinterpret_cast<const float4*>(weighted + (size_t)e0 * NS);
  const float4* w1p4  = reinterpret_cast<const float4*>(weighted + (size_t)e1 * NS);

  float* xw = &xrow[wv][0];
  float* aw = &acc[wv][0];

  // software-pipelined scatter over NS (64 iters x 64 lanes x 4 elems)
  int s4 = lane;
  int4   m = mask4[s4];
  float4 a = w0p4[s4];
  float4 b = w1p4[s4];
#pragma unroll 1
  for (int iter = 0; iter < 64; ++iter) {
    const int s4n = (s4 + 64 <= 4095) ? s4 + 64 : 4095;  // clamped prefetch
    int4   mN = mask4[s4n];
    float4 aN = w0p4[s4n];
    float4 bN = w1p4[s4n];

    float4 v;
    v.x = fmaf(rw0, a.x, rw1 * b.x);
    v.y = fmaf(rw0, a.y, rw1 * b.y);
    v.z = fmaf(rw0, a.z, rw1 * b.z);
    v.w = fmaf(rw0, a.w, rw1 * b.w);
    {
      int r = m.x >> LOGH, c = m.x & (H - 1);
      atomicAdd(&aw[r], xw[c] * v.x);
    }
    {
      int r = m.y >> LOGH, c = m.y & (H - 1);
      atomicAdd(&aw[r], xw[c] * v.y);
    }
    {
      int r = m.z >> LOGH, c = m.z & (H - 1);
      atomicAdd(&aw[r], xw[c] * v.z);
    }
    {
      int r = m.w >> LOGH, c = m.w & (H - 1);
      atomicAdd(&aw[r], xw[c] * v.w);
    }
    m = mN; a = aN; b = bN;
    s4 += 64;
  }
  __syncthreads();

  // epilogue: out[t] += acc (wave w owns its token row)
  {
    float4* orow = reinterpret_cast<float4*>(out + (size_t)t * H);
    const float4* arow = reinterpret_cast<const float4*>(aw);
#pragma unroll
    for (int i = 0; i < 8; ++i) {
      int idx = lane + i * 64;
      float4 o = orow[idx];
      float4 av = arow[idx];
      o.x += av.x; o.y += av.y; o.z += av.z; o.w += av.w;
      orow[idx] = o;
    }
  }
}

extern "C" void kernel_launch(void* const* d_in, const int* in_sizes, int n_in,
                              void* d_out, int out_size, void* d_ws, size_t ws_size,
                              hipStream_t stream) {
  const float* x          = (const float*)d_in[0];
  const float* gate_w     = (const float*)d_in[1];
  const float* W          = (const float*)d_in[2];
  const float* atoms      = (const float*)d_in[3];
  const float* eaw        = (const float*)d_in[4];
  const float* importance = (const float*)d_in[5];
  const int*   mask_idx   = (const int*)d_in[6];
  float* out = (float*)d_out;

  char* ws = (char*)d_ws;
  unsigned short* xb = (unsigned short*)ws;                                // 16 MB
  unsigned short* wb = (unsigned short*)(ws + (size_t)T_TOK * H * 2);      // 8 MB
  float* weighted = (float*)(ws + (size_t)T_TOK * H * 2 + (size_t)H * H * 2);  // 512 KB
  float4* tokInfo = (float4*)(ws + (size_t)T_TOK * H * 2 + (size_t)H * H * 2 +
                              (size_t)NEXP * NS * 4);                      // 64 KB

  cvt_kernel<<<2048, 256, 0, stream>>>(x, W, xb, wb);
  weighted_kernel<<<64, 256, 0, stream>>>(eaw, atoms, importance, weighted);
  gate_kernel<<<T_TOK / 4, 256, 0, stream>>>(x, gate_w, tokInfo);
  gemm_kernel<<<dim3(H / 128, T_TOK / 128), 256, 0, stream>>>(xb, wb, out);
  scatter_kernel<<<T_TOK / 4, 256, 0, stream>>>(x, weighted, mask_idx, tokInfo, out);
}